// Round 1
// baseline (74.776 us; speedup 1.0000x reference)
//
#include <hip/hip_runtime.h>
#include <math.h>

#define TABN 2048
#define EPB 4            // LUT entries per block (one wave per block)
#define ROWS_PER_WAVE 8
#define D 1000
#define DV4 250          // 1000 floats = 250 float4, row stride 4000B is 16B-aligned

// ---------------- LUT kernel: tabulate f(s) = sigmoid(MLP(s)) over s in [-1,1] ----------
__global__ __launch_bounds__(64) void lut_kernel(
    const float* __restrict__ w1, const float* __restrict__ b1,
    const float* __restrict__ w2, const float* __restrict__ b2,
    const float* __restrict__ w3, const float* __restrict__ b3,
    const float* __restrict__ w4, const float* __restrict__ b4,
    float* __restrict__ lut)
{
    __shared__ float h1[EPB][512];
    __shared__ float h2s[EPB][64];
    const int lane = threadIdx.x;           // 64 threads = 1 wave
    const int e0 = blockIdx.x * EPB;

    float s[EPB];
#pragma unroll
    for (int e = 0; e < EPB; ++e)
        s[e] = -1.0f + 2.0f * (float)(e0 + e) / (float)(TABN - 1);

    // layer 1: 1 -> 512
    for (int j = lane; j < 512; j += 64) {
        float wj = w1[j], bj = b1[j];
#pragma unroll
        for (int e = 0; e < EPB; ++e) {
            float v = fmaf(wj, s[e], bj);
            h1[e][j] = v > 0.0f ? v : 0.0f;
        }
    }
    __syncthreads();

    // layer 2: 512 -> 64, lane = output unit k; w2 read once per EPB entries
    float acc[EPB];
    {
        float bk = b2[lane];
#pragma unroll
        for (int e = 0; e < EPB; ++e) acc[e] = bk;
    }
    for (int j = 0; j < 512; ++j) {
        float w = w2[j * 64 + lane];
#pragma unroll
        for (int e = 0; e < EPB; ++e)
            acc[e] = fmaf(w, h1[e][j], acc[e]);
    }
#pragma unroll
    for (int e = 0; e < EPB; ++e)
        h2s[e][lane] = acc[e] > 0.0f ? acc[e] : 0.0f;
    __syncthreads();

    // layer 3 (64 -> 32) + layer 4 partial (32 -> 1): lanes 0..31, m = lane
    float part[EPB];
#pragma unroll
    for (int e = 0; e < EPB; ++e) part[e] = 0.0f;
    if (lane < 32) {
        float b3m = b3[lane];
        float w4m = w4[lane];
#pragma unroll
        for (int e = 0; e < EPB; ++e) {
            float a = b3m;
            for (int k = 0; k < 64; ++k)
                a = fmaf(w3[k * 32 + lane], h2s[e][k], a);
            float h3 = a > 0.0f ? a : 0.0f;
            part[e] = h3 * w4m;
        }
    }
    // full-wave tree reduce (lanes >=32 contribute 0)
#pragma unroll
    for (int off = 32; off >= 1; off >>= 1) {
#pragma unroll
        for (int e = 0; e < EPB; ++e)
            part[e] += __shfl_down(part[e], off, 64);
    }
    if (lane == 0) {
        float b4v = b4[0];
#pragma unroll
        for (int e = 0; e < EPB; ++e) {
            float z = part[e] + b4v;
            lut[e0 + e] = 1.0f / (1.0f + expf(-z));
        }
    }
}

// ---------------- main kernel: cosine sim + LUT lerp ----------------
__device__ __forceinline__ float dot4(float4 a, float4 b, float acc) {
    acc = fmaf(a.x, b.x, acc);
    acc = fmaf(a.y, b.y, acc);
    acc = fmaf(a.z, b.z, acc);
    acc = fmaf(a.w, b.w, acc);
    return acc;
}

__global__ __launch_bounds__(256) void sim_kernel(
    const float* __restrict__ query, const float* __restrict__ emb,
    const float* __restrict__ lut, float* __restrict__ out, int N)
{
    const int lane = threadIdx.x & 63;
    const int wave = blockIdx.x * (blockDim.x >> 6) + (threadIdx.x >> 6);

    const float4 zero4 = make_float4(0.f, 0.f, 0.f, 0.f);
    const float4* q4 = (const float4*)query;
    // q fragments in registers, reused for all rows this wave handles
    float4 q0 = q4[lane];
    float4 q1 = q4[lane + 64];
    float4 q2 = q4[lane + 128];
    float4 q3 = (lane < DV4 - 192) ? q4[lane + 192] : zero4;

    // ||q||^2 (each element counted exactly once across the wave)
    float nq = 0.f;
    nq = dot4(q0, q0, nq); nq = dot4(q1, q1, nq);
    nq = dot4(q2, q2, nq); nq = dot4(q3, q3, nq);
#pragma unroll
    for (int off = 32; off >= 1; off >>= 1) nq += __shfl_xor(nq, off, 64);
    const float qn = sqrtf(nq);

#pragma unroll 1
    for (int r = 0; r < ROWS_PER_WAVE; ++r) {
        const int row = wave * ROWS_PER_WAVE + r;
        if (row >= N) break;
        const float4* e4 = (const float4*)(emb + (size_t)row * D);
        float4 a0 = e4[lane];
        float4 a1 = e4[lane + 64];
        float4 a2 = e4[lane + 128];
        float4 a3 = (lane < DV4 - 192) ? e4[lane + 192] : zero4;

        float dot = 0.f, nn = 0.f;
        dot = dot4(a0, q0, dot); nn = dot4(a0, a0, nn);
        dot = dot4(a1, q1, dot); nn = dot4(a1, a1, nn);
        dot = dot4(a2, q2, dot); nn = dot4(a2, a2, nn);
        dot = dot4(a3, q3, dot); nn = dot4(a3, a3, nn);
#pragma unroll
        for (int off = 32; off >= 1; off >>= 1) {
            dot += __shfl_xor(dot, off, 64);
            nn  += __shfl_xor(nn,  off, 64);
        }
        if (lane == 0) {
            float sim = dot / fmaxf(sqrtf(nn) * qn, 1e-8f);
            float t = (sim + 1.0f) * (0.5f * (float)(TABN - 1));
            t = fminf(fmaxf(t, 0.0f), (float)(TABN - 1));
            int i0 = (int)t;
            if (i0 > TABN - 2) i0 = TABN - 2;
            float fr = t - (float)i0;
            float v0 = lut[i0], v1 = lut[i0 + 1];
            out[row] = fmaf(v1 - v0, fr, v0);
        }
    }
}

extern "C" void kernel_launch(void* const* d_in, const int* in_sizes, int n_in,
                              void* d_out, int out_size, void* d_ws, size_t ws_size,
                              hipStream_t stream) {
    const float* query = (const float*)d_in[0];
    const float* emb   = (const float*)d_in[1];
    const float* w1    = (const float*)d_in[2];
    const float* b1    = (const float*)d_in[3];
    const float* w2    = (const float*)d_in[4];
    const float* b2    = (const float*)d_in[5];
    const float* w3    = (const float*)d_in[6];
    const float* b3    = (const float*)d_in[7];
    const float* w4    = (const float*)d_in[8];
    const float* b4    = (const float*)d_in[9];
    float* lut = (float*)d_ws;
    float* out = (float*)d_out;
    const int N = in_sizes[1] / D;   // 65536

    lut_kernel<<<TABN / EPB, 64, 0, stream>>>(w1, b1, w2, b2, w3, b3, w4, b4, lut);

    const int waves = (N + ROWS_PER_WAVE - 1) / ROWS_PER_WAVE;
    const int blocks = (waves + 3) / 4;      // 4 waves (256 threads) per block
    sim_kernel<<<blocks, 256, 0, stream>>>(query, emb, lut, out, N);
}